// Round 1
// baseline (448.809 us; speedup 1.0000x reference)
//
#include <hip/hip_runtime.h>

#define NE 4000
#define NI 1000
#define NT 5000            // total neurons
#define PI_F 3.14159265358979323846f

// d_out layout (floats): [0,T) Out | [T, T+NT*T) V | next NT*T g | next NT*T spk

__global__ void zero_out(float* __restrict__ out, int T, int* __restrict__ flag)
{
    long idx = (long)blockIdx.x * blockDim.x + threadIdx.x;
    long stride = (long)gridDim.x * blockDim.x;
    if (idx == 0) *flag = 0x7fffffff;
    const long NTT4 = (long)NT * T / 4;
    float4 z = make_float4(0.f, 0.f, 0.f, 0.f);
    float4* g4 = (float4*)(out + T + (long)NT * T);
    float4* s4 = (float4*)(out + T + 2L * NT * T);
    for (long k = idx; k < NTT4; k += stride) { g4[k] = z; s4[k] = z; }
    if (idx < T / 4) ((float4*)out)[idx] = z;
}

// Optimistic decoupled integration: valid as long as no neuron anywhere spikes.
// Detects the first spike exactly (trajectories are exact up to that step).
__global__ __launch_bounds__(64) void sim_nospike(
    const float* __restrict__ Input, const float* __restrict__ dtp,
    float* __restrict__ out, int T, int* __restrict__ flag)
{
    int i = blockIdx.x * 64 + threadIdx.x;
    if (i >= NT) return;
    const float dt = dtp[0];
    const float gl = (i < NE) ? 0.08f : 0.1f;
    const float C0 = (float)(2.0 / 7.0);
    const float* inrow = Input + (long)i * T;
    float* vrow = out + T + (long)i * T;
    vrow[0] = -58.5f;                      // theta2V(0)
    float ph = 0.f;
    float c = 1.f;                          // cos(ph)
    float inp_next = inrow[1];
    for (int t = 1; t < T; ++t) {
        float inp = inp_next;
        int tn = (t + 1 < T) ? (t + 1) : t;
        inp_next = inrow[tn];               // prefetch next input
        float ph2 = ph + (-gl * c + C0 * (1.f + c) * inp) * dt;  // g == 0 path
        if (ph2 >= PI_F) { atomicMin(flag, t); ph2 -= 2.f * PI_F; }
        float s2 = __sinf(ph2);
        float c2 = __cosf(ph2);
        // tan(x/2) = sin(x)/(1+cos(x))
        vrow[t] = fmaf(3.5f, __fdividef(s2, 1.f + c2), -58.5f);
        ph = ph2; c = c2;
    }
}

// Exact sequential fallback (only executes if a spike was detected).
__global__ __launch_bounds__(1024) void fallback(
    const float* __restrict__ Input, const float* __restrict__ conn,
    const float* __restrict__ Wout, const float* __restrict__ dtp,
    const int* __restrict__ tauEp, const int* __restrict__ tauIp,
    float* __restrict__ out, int T, const int* __restrict__ flag)
{
    if (*flag == 0x7fffffff) return;        // uniform: no spikes -> optimistic path valid

    const float dt = *dtp;
    const float tauE = (float)(*tauEp), tauI = (float)(*tauIp);
    const float C0 = (float)(2.0 / 7.0);
    const float C1 = (float)(117.0 / 7.0);
    const float C2 = (float)(-23.0 / 7.0);
    const int tid = threadIdx.x;
    const int BLK = 1024;
    const int K = 5;                        // 5*1024 >= 5000

    __shared__ int cntE, cntI;
    __shared__ int listE[NE];
    __shared__ int listI[NI];
    __shared__ float red[1024];

    float gA[K], gB[K], gC[K], ph[K];
    for (int k = 0; k < K; ++k) { gA[k] = gB[k] = gC[k] = 0.f; ph[k] = 0.f; }
    if (tid == 0) { cntE = 0; cntI = 0; }

    float* Vout = out + T;
    float* Gout = out + T + (long)NT * T;
    float* Sout = out + T + 2L * (long)NT * T;
    for (int k = 0; k < K; ++k) {
        int i = tid + k * BLK;
        if (i < NT) Vout[(long)i * T] = -58.5f;
    }
    __syncthreads();

    for (int t = 1; t < T; ++t) {
        int nE = cntE, nI = cntI;           // spikes from step t-1
        float outpart = 0.f;
        for (int k = 0; k < K; ++k) {
            int i = tid + k * BLK;
            if (i >= NT) break;
            const float* crow = conn + (long)i * NT;
            float mA = 0.f, mB = 0.f;
            for (int j = 0; j < nE; ++j) mA += crow[listE[j]];
            for (int j = 0; j < nI; ++j) mB += crow[listI[j]];
            bool isE = i < NE;
            float tau = isE ? tauE : tauI;
            float gpA = isE ? 0.004069f : 0.003276f;
            float gpB = isE ? 0.02672f  : 0.02138f;
            gA[k] = gA[k] + (-gA[k] / tau + gpA * mA) * dt;
            gB[k] = gB[k] + (-gB[k] / tau + gpB * mB) * dt;
            gC[k] = gC[k] + (-gC[k] / tau + gpA * mA + gpB * mB) * dt;
            Gout[(long)i * T + t] = gC[k];
            outpart += gC[k] * Wout[i];
        }
        __syncthreads();                    // all done reading lists
        if (tid == 0) { cntE = 0; cntI = 0; }
        red[tid] = outpart;
        __syncthreads();
        for (int sd = BLK / 2; sd > 0; sd >>= 1) {
            if (tid < sd) red[tid] += red[tid + sd];
            __syncthreads();
        }
        if (tid == 0) out[t] = red[0] / (float)NT;

        for (int k = 0; k < K; ++k) {
            int i = tid + k * BLK;
            if (i >= NT) break;
            bool isE = i < NE;
            float gl = isE ? 0.08f : 0.1f;
            float inp = Input[(long)i * T + t];
            float s, c;
            sincosf(ph[k], &s, &c);
            float ph2 = ph[k] + (-gl * c + C0 * (1.f + c) * inp
                                 + gA[k] * (C1 * (1.f + c) - s)
                                 + gB[k] * (C2 * (1.f + c) - s)) * dt;
            float spkv = 0.f;
            if (ph2 >= PI_F) {
                spkv = 1.f;
                ph2 -= 2.f * PI_F;
                int pos = isE ? atomicAdd(&cntE, 1) : atomicAdd(&cntI, 1);
                if (isE) listE[pos] = i; else listI[pos] = i;   // full column index
            }
            ph[k] = ph2;
            Sout[(long)i * T + t] = spkv;
            Vout[(long)i * T + t] = fmaf(3.5f, tanf(ph2 * 0.5f), -58.5f);
        }
        __syncthreads();                    // lists complete for next step
    }
}

extern "C" void kernel_launch(void* const* d_in, const int* in_sizes, int n_in,
                              void* d_out, int out_size, void* d_ws, size_t ws_size,
                              hipStream_t stream)
{
    const float* dt    = (const float*)d_in[0];
    const float* Input = (const float*)d_in[1];
    const float* conn  = (const float*)d_in[2];
    const float* Wout  = (const float*)d_in[3];
    const int*   tauE  = (const int*)d_in[6];
    const int*   tauI  = (const int*)d_in[7];
    int T = in_sizes[1] / NT;
    float* out = (float*)d_out;
    int* flag = (int*)d_ws;

    zero_out<<<512, 256, 0, stream>>>(out, T, flag);
    sim_nospike<<<(NT + 63) / 64, 64, 0, stream>>>(Input, dt, out, T, flag);
    fallback<<<1, 1024, 0, stream>>>(Input, conn, Wout, dt, tauE, tauI, out, T, flag);
}

// Round 2
// 234.124 us; speedup vs baseline: 1.9170x; 1.9170x over previous
//
#include <hip/hip_runtime.h>

#define NE 4000
#define NI 1000
#define NT 5000            // total neurons
#define PI_F 3.14159265358979323846f
#define CH 40              // timesteps per register chunk (T=1000 -> 25 chunks)

// d_out layout (floats): [0,T) Out | [T, T+NT*T) V | next NT*T g | next NT*T spk

__global__ void zero_out(float* __restrict__ out, int T, int* __restrict__ flag)
{
    long idx = (long)blockIdx.x * blockDim.x + threadIdx.x;
    long stride = (long)gridDim.x * blockDim.x;
    if (idx == 0) *flag = 0x7fffffff;
    const long NTT4 = (long)NT * T / 4;
    float4 z = make_float4(0.f, 0.f, 0.f, 0.f);
    float4* g4 = (float4*)(out + T + (long)NT * T);
    float4* s4 = (float4*)(out + T + 2L * NT * T);
    for (long k = idx; k < NTT4; k += stride) { g4[k] = z; s4[k] = z; }
    if (idx < T / 4) ((float4*)out)[idx] = z;
}

// Optimistic decoupled integration: valid as long as no neuron anywhere spikes.
// Chunked register staging: Input row loaded 40 steps ahead (latency hidden),
// V row stored as float4s. Critical path = the fma->cos recursion (~25 cyc/step).
__global__ __launch_bounds__(64) void sim_nospike(
    const float* __restrict__ Input, const float* __restrict__ dtp,
    float* __restrict__ out, int T, int* __restrict__ flag)
{
    int i = blockIdx.x * 64 + threadIdx.x;
    if (i >= NT) return;
    const float dt = dtp[0];
    const float gl = (i < NE) ? 0.08f : 0.1f;
    const float C0 = (float)(2.0 / 7.0);
    const float* inrow = Input + (long)i * T;
    float* vrow = out + T + (long)i * T;

    float ph = 0.f;       // phase
    float cc = 1.f;       // cos(phase)
    int spkt = 0x7fffffff;

    float buf[CH], nbuf[CH], vbuf[CH];
    const int nch = T / CH;

    if (nch > 0) {
        #pragma unroll
        for (int q = 0; q < CH / 4; ++q)
            *(float4*)(buf + 4 * q) = *(const float4*)(inrow + 4 * q);
    }

    for (int c = 0; c < nch; ++c) {
        if (c + 1 < nch) {                       // prefetch next chunk (~1000cy early)
            const float* src = inrow + (c + 1) * CH;
            #pragma unroll
            for (int q = 0; q < CH / 4; ++q)
                *(float4*)(nbuf + 4 * q) = *(const float4*)(src + 4 * q);
        }
        #pragma unroll
        for (int u = 0; u < CH; ++u) {
            int t = c * CH + u;
            if (t > 0) {                         // wave-uniform branch
                float inp = buf[u];
                ph = fmaf(fmaf(C0 * inp, 1.f + cc, -gl * cc), dt, ph);
                spkt = (ph >= PI_F && t < spkt) ? t : spkt;   // branchless record
            }
            float s = __sinf(ph);
            cc = __cosf(ph);
            // theta2V: tan(x/2) = sin(x)/(1+cos(x))
            vbuf[u] = fmaf(3.5f, __fdividef(s, 1.f + cc), -58.5f);
        }
        float* dst = vrow + c * CH;
        #pragma unroll
        for (int q = 0; q < CH / 4; ++q)
            *(float4*)(dst + 4 * q) = *(const float4*)(vbuf + 4 * q);
        #pragma unroll
        for (int q = 0; q < CH; ++q) buf[q] = nbuf[q];
    }
    // scalar tail (T not divisible by CH) — unused for T=1000
    for (int t = nch * CH; t < T; ++t) {
        if (t > 0) {
            float inp = inrow[t];
            ph = fmaf(fmaf(C0 * inp, 1.f + cc, -gl * cc), dt, ph);
            spkt = (ph >= PI_F && t < spkt) ? t : spkt;
        }
        float s = __sinf(ph);
        cc = __cosf(ph);
        vrow[t] = fmaf(3.5f, __fdividef(s, 1.f + cc), -58.5f);
    }

    if (spkt != 0x7fffffff) atomicMin(flag, spkt);
}

// Exact sequential fallback (only executes if a spike was detected).
__global__ __launch_bounds__(1024) void fallback(
    const float* __restrict__ Input, const float* __restrict__ conn,
    const float* __restrict__ Wout, const float* __restrict__ dtp,
    const int* __restrict__ tauEp, const int* __restrict__ tauIp,
    float* __restrict__ out, int T, const int* __restrict__ flag)
{
    if (*flag == 0x7fffffff) return;        // uniform: no spikes -> optimistic path valid

    const float dt = *dtp;
    const float tauE = (float)(*tauEp), tauI = (float)(*tauIp);
    const float C0 = (float)(2.0 / 7.0);
    const float C1 = (float)(117.0 / 7.0);
    const float C2 = (float)(-23.0 / 7.0);
    const int tid = threadIdx.x;
    const int BLK = 1024;
    const int K = 5;                        // 5*1024 >= 5000

    __shared__ int cntE, cntI;
    __shared__ int listE[NE];
    __shared__ int listI[NI];
    __shared__ float red[1024];

    float gA[K], gB[K], gC[K], ph[K];
    for (int k = 0; k < K; ++k) { gA[k] = gB[k] = gC[k] = 0.f; ph[k] = 0.f; }
    if (tid == 0) { cntE = 0; cntI = 0; }

    float* Vout = out + T;
    float* Gout = out + T + (long)NT * T;
    float* Sout = out + T + 2L * (long)NT * T;
    for (int k = 0; k < K; ++k) {
        int i = tid + k * BLK;
        if (i < NT) Vout[(long)i * T] = -58.5f;
    }
    __syncthreads();

    for (int t = 1; t < T; ++t) {
        int nE = cntE, nI = cntI;           // spikes from step t-1
        float outpart = 0.f;
        for (int k = 0; k < K; ++k) {
            int i = tid + k * BLK;
            if (i >= NT) break;
            const float* crow = conn + (long)i * NT;
            float mA = 0.f, mB = 0.f;
            for (int j = 0; j < nE; ++j) mA += crow[listE[j]];
            for (int j = 0; j < nI; ++j) mB += crow[listI[j]];
            bool isE = i < NE;
            float tau = isE ? tauE : tauI;
            float gpA = isE ? 0.004069f : 0.003276f;
            float gpB = isE ? 0.02672f  : 0.02138f;
            gA[k] = gA[k] + (-gA[k] / tau + gpA * mA) * dt;
            gB[k] = gB[k] + (-gB[k] / tau + gpB * mB) * dt;
            gC[k] = gC[k] + (-gC[k] / tau + gpA * mA + gpB * mB) * dt;
            Gout[(long)i * T + t] = gC[k];
            outpart += gC[k] * Wout[i];
        }
        __syncthreads();                    // all done reading lists
        if (tid == 0) { cntE = 0; cntI = 0; }
        red[tid] = outpart;
        __syncthreads();
        for (int sd = BLK / 2; sd > 0; sd >>= 1) {
            if (tid < sd) red[tid] += red[tid + sd];
            __syncthreads();
        }
        if (tid == 0) out[t] = red[0] / (float)NT;

        for (int k = 0; k < K; ++k) {
            int i = tid + k * BLK;
            if (i >= NT) break;
            bool isE = i < NE;
            float gl = isE ? 0.08f : 0.1f;
            float inp = Input[(long)i * T + t];
            float s, c;
            sincosf(ph[k], &s, &c);
            float ph2 = ph[k] + (-gl * c + C0 * (1.f + c) * inp
                                 + gA[k] * (C1 * (1.f + c) - s)
                                 + gB[k] * (C2 * (1.f + c) - s)) * dt;
            float spkv = 0.f;
            if (ph2 >= PI_F) {
                spkv = 1.f;
                ph2 -= 2.f * PI_F;
                int pos = isE ? atomicAdd(&cntE, 1) : atomicAdd(&cntI, 1);
                if (isE) listE[pos] = i; else listI[pos] = i;   // full column index
            }
            ph[k] = ph2;
            Sout[(long)i * T + t] = spkv;
            Vout[(long)i * T + t] = fmaf(3.5f, tanf(ph2 * 0.5f), -58.5f);
        }
        __syncthreads();                    // lists complete for next step
    }
}

extern "C" void kernel_launch(void* const* d_in, const int* in_sizes, int n_in,
                              void* d_out, int out_size, void* d_ws, size_t ws_size,
                              hipStream_t stream)
{
    const float* dt    = (const float*)d_in[0];
    const float* Input = (const float*)d_in[1];
    const float* conn  = (const float*)d_in[2];
    const float* Wout  = (const float*)d_in[3];
    const int*   tauE  = (const int*)d_in[6];
    const int*   tauI  = (const int*)d_in[7];
    int T = in_sizes[1] / NT;
    float* out = (float*)d_out;
    int* flag = (int*)d_ws;

    zero_out<<<1024, 256, 0, stream>>>(out, T, flag);
    sim_nospike<<<(NT + 63) / 64, 64, 0, stream>>>(Input, dt, out, T, flag);
    fallback<<<1, 1024, 0, stream>>>(Input, conn, Wout, dt, tauE, tauI, out, T, flag);
}

// Round 3
// 210.839 us; speedup vs baseline: 2.1287x; 1.1104x over previous
//
#include <hip/hip_runtime.h>

#define NE 4000
#define NI 1000
#define NT 5000            // total neurons
#define PI_F 3.14159265358979323846f

// d_out layout (floats): [0,T) Out | [T, T+NT*T) V | next NT*T g | next NT*T spk

__global__ void zero_out(float* __restrict__ out, int T, int* __restrict__ flag)
{
    long idx = (long)blockIdx.x * blockDim.x + threadIdx.x;
    long stride = (long)gridDim.x * blockDim.x;
    if (idx == 0) *flag = 0x7fffffff;
    const long n4 = (long)NT * T / 2;       // g + spk contiguous, in float4s
    float4 z = make_float4(0.f, 0.f, 0.f, 0.f);
    float4* gz = (float4*)(out + T + (long)NT * T);
    for (long k = idx; k < n4; k += stride) gz[k] = z;
    if (idx < T / 4) ((float4*)out)[idx] = z;
}

__device__ __forceinline__ float4 scale4(float4 r, float k) {
    return make_float4(r.x * k, r.y * k, r.z * k, r.w * k);
}

// batched 4-way reciprocal: returns -58.5 + nu/de componentwise (1 v_rcp total)
__device__ __forceinline__ float4 v4div(float4 nu, float4 de) {
    float p01   = de.x * de.y;
    float p012  = p01 * de.z;
    float p0123 = p012 * de.w;
    float r     = __builtin_amdgcn_rcpf(p0123);
    float rw    = r * p012;       // 1/w
    float r012  = r * de.w;       // 1/(x*y*z)
    float rz    = r012 * p01;     // 1/z
    float r01   = r012 * de.z;    // 1/(x*y)
    float ry    = r01 * de.x;     // 1/y
    float rx    = r01 * de.y;     // 1/x
    return make_float4(fmaf(nu.x, rx, -58.5f), fmaf(nu.y, ry, -58.5f),
                       fmaf(nu.z, rz, -58.5f), fmaf(nu.w, rw, -58.5f));
}

// one Euler step via small-angle rotation of (ss,cc); A = C0*dt*input (pre-scaled)
#define STEP(A, NU, DE) {                       \
    float a_  = (A);                            \
    float cf_ = a_ + bc;                        \
    float d_  = fmaf(cc, cf_, a_);              \
    float d2_ = d_ * d_;                        \
    float cd_ = fmaf(d2_, -0.5f, 1.0f);         \
    float sd_ = ss * d_;                        \
    float cs_ = cc * d_;                        \
    float c2_ = fmaf(cc, cd_, -sd_);            \
    float s2_ = fmaf(ss, cd_, cs_);             \
    ph += d_; phmax = fmaxf(phmax, ph);         \
    cc = c2_; ss = s2_;                         \
    NU = 3.5f * s2_; DE = 1.0f + c2_;           \
}

#define GROUP4(X, OFF) {                                    \
    float4 nu_, de_;                                        \
    STEP(X.x, nu_.x, de_.x); STEP(X.y, nu_.y, de_.y);       \
    STEP(X.z, nu_.z, de_.z); STEP(X.w, nu_.w, de_.w);       \
    *(float4*)(vrow + (OFF)) = v4div(nu_, de_);             \
}

// first group of chunk 0: t=0 does no update, V[0] = theta2V(0) = -58.5
#define GROUP4_FIRST(X, OFF) {                              \
    float4 nu_, de_;                                        \
    nu_.x = 0.f; de_.x = 1.f;                               \
    STEP(X.y, nu_.y, de_.y);                                \
    STEP(X.z, nu_.z, de_.z); STEP(X.w, nu_.w, de_.w);       \
    *(float4*)(vrow + (OFF)) = v4div(nu_, de_);             \
}

// Optimistic decoupled integration (valid while no neuron spikes; detects spikes).
// All state in explicit float4 registers — no indexed arrays, no scratch spill.
__global__ __launch_bounds__(64) void sim_nospike(
    const float* __restrict__ Input, const float* __restrict__ dtp,
    float* __restrict__ out, int T, int* __restrict__ flag)
{
    int i = blockIdx.x * 64 + threadIdx.x;
    if (i >= NT) return;
    const float dt = dtp[0];
    const float gl = (i < NE) ? 0.08f : 0.1f;
    const float k  = (float)(2.0 / 7.0) * dt;   // C0*dt
    const float bc = -gl * dt;
    const float* ip = Input + (long)i * T;
    float* vrow = out + T + (long)i * T;

    float cc = 1.f, ss = 0.f, ph = 0.f, phmax = -1e30f;

    const int C = T / 16;                       // full 16-step chunks
    // prefetch chunk 0 (scaled into registers)
    float4 cx0 = scale4(*(const float4*)(ip + 0),  k);
    float4 cx1 = scale4(*(const float4*)(ip + 4),  k);
    float4 cx2 = scale4(*(const float4*)(ip + 8),  k);
    float4 cx3 = scale4(*(const float4*)(ip + 12), k);

    for (int c = 0; c < C; ++c) {
        float4 n0, n1, n2, n3;
        if (c + 1 < C) {                        // issue next chunk's loads early
            const float* np_ = ip + (c + 1) * 16;
            n0 = *(const float4*)(np_ + 0);
            n1 = *(const float4*)(np_ + 4);
            n2 = *(const float4*)(np_ + 8);
            n3 = *(const float4*)(np_ + 12);
        }
        int off = c * 16;
        if (c == 0) { GROUP4_FIRST(cx0, 0); }
        else        { GROUP4(cx0, off); }
        GROUP4(cx1, off + 4);
        GROUP4(cx2, off + 8);
        GROUP4(cx3, off + 12);
        if (c + 1 < C) {
            cx0 = scale4(n0, k); cx1 = scale4(n1, k);
            cx2 = scale4(n2, k); cx3 = scale4(n3, k);
        }
    }
    // scalar tail (T=1000 -> 8 steps)
    for (int t = 16 * C; t < T; ++t) {
        float a_  = ip[t] * k;
        float cf_ = a_ + bc;
        float d_  = fmaf(cc, cf_, a_);
        float d2_ = d_ * d_;
        float cd_ = fmaf(d2_, -0.5f, 1.0f);
        float c2_ = fmaf(cc, cd_, -(ss * d_));
        float s2_ = fmaf(ss, cd_, cc * d_);
        ph += d_; phmax = fmaxf(phmax, ph);
        cc = c2_; ss = s2_;
        vrow[t] = fmaf(3.5f * s2_, __builtin_amdgcn_rcpf(1.0f + c2_), -58.5f);
    }

    if (phmax >= PI_F) atomicMin(flag, 0);
}

// Exact sequential fallback (only executes if a spike was detected).
__global__ __launch_bounds__(1024) void fallback(
    const float* __restrict__ Input, const float* __restrict__ conn,
    const float* __restrict__ Wout, const float* __restrict__ dtp,
    const int* __restrict__ tauEp, const int* __restrict__ tauIp,
    float* __restrict__ out, int T, const int* __restrict__ flag)
{
    if (*flag == 0x7fffffff) return;        // uniform: no spikes -> optimistic path valid

    const float dt = *dtp;
    const float tauE = (float)(*tauEp), tauI = (float)(*tauIp);
    const float C0 = (float)(2.0 / 7.0);
    const float C1 = (float)(117.0 / 7.0);
    const float C2 = (float)(-23.0 / 7.0);
    const int tid = threadIdx.x;
    const int BLK = 1024;
    const int K = 5;                        // 5*1024 >= 5000

    __shared__ int cntE, cntI;
    __shared__ int listE[NE];
    __shared__ int listI[NI];
    __shared__ float red[1024];

    float gA[K], gB[K], gC[K], ph[K];
    for (int k = 0; k < K; ++k) { gA[k] = gB[k] = gC[k] = 0.f; ph[k] = 0.f; }
    if (tid == 0) { cntE = 0; cntI = 0; }

    float* Vout = out + T;
    float* Gout = out + T + (long)NT * T;
    float* Sout = out + T + 2L * (long)NT * T;
    for (int k = 0; k < K; ++k) {
        int i = tid + k * BLK;
        if (i < NT) Vout[(long)i * T] = -58.5f;
    }
    __syncthreads();

    for (int t = 1; t < T; ++t) {
        int nE = cntE, nI = cntI;           // spikes from step t-1
        float outpart = 0.f;
        for (int k = 0; k < K; ++k) {
            int i = tid + k * BLK;
            if (i >= NT) break;
            const float* crow = conn + (long)i * NT;
            float mA = 0.f, mB = 0.f;
            for (int j = 0; j < nE; ++j) mA += crow[listE[j]];
            for (int j = 0; j < nI; ++j) mB += crow[listI[j]];
            bool isE = i < NE;
            float tau = isE ? tauE : tauI;
            float gpA = isE ? 0.004069f : 0.003276f;
            float gpB = isE ? 0.02672f  : 0.02138f;
            gA[k] = gA[k] + (-gA[k] / tau + gpA * mA) * dt;
            gB[k] = gB[k] + (-gB[k] / tau + gpB * mB) * dt;
            gC[k] = gC[k] + (-gC[k] / tau + gpA * mA + gpB * mB) * dt;
            Gout[(long)i * T + t] = gC[k];
            outpart += gC[k] * Wout[i];
        }
        __syncthreads();                    // all done reading lists
        if (tid == 0) { cntE = 0; cntI = 0; }
        red[tid] = outpart;
        __syncthreads();
        for (int sd = BLK / 2; sd > 0; sd >>= 1) {
            if (tid < sd) red[tid] += red[tid + sd];
            __syncthreads();
        }
        if (tid == 0) out[t] = red[0] / (float)NT;

        for (int k = 0; k < K; ++k) {
            int i = tid + k * BLK;
            if (i >= NT) break;
            bool isE = i < NE;
            float gl = isE ? 0.08f : 0.1f;
            float inp = Input[(long)i * T + t];
            float s, c;
            sincosf(ph[k], &s, &c);
            float ph2 = ph[k] + (-gl * c + C0 * (1.f + c) * inp
                                 + gA[k] * (C1 * (1.f + c) - s)
                                 + gB[k] * (C2 * (1.f + c) - s)) * dt;
            float spkv = 0.f;
            if (ph2 >= PI_F) {
                spkv = 1.f;
                ph2 -= 2.f * PI_F;
                int pos = isE ? atomicAdd(&cntE, 1) : atomicAdd(&cntI, 1);
                if (isE) listE[pos] = i; else listI[pos] = i;   // full column index
            }
            ph[k] = ph2;
            Sout[(long)i * T + t] = spkv;
            Vout[(long)i * T + t] = fmaf(3.5f, tanf(ph2 * 0.5f), -58.5f);
        }
        __syncthreads();                    // lists complete for next step
    }
}

extern "C" void kernel_launch(void* const* d_in, const int* in_sizes, int n_in,
                              void* d_out, int out_size, void* d_ws, size_t ws_size,
                              hipStream_t stream)
{
    const float* dt    = (const float*)d_in[0];
    const float* Input = (const float*)d_in[1];
    const float* conn  = (const float*)d_in[2];
    const float* Wout  = (const float*)d_in[3];
    const int*   tauE  = (const int*)d_in[6];
    const int*   tauI  = (const int*)d_in[7];
    int T = in_sizes[1] / NT;
    float* out = (float*)d_out;
    int* flag = (int*)d_ws;

    zero_out<<<1024, 256, 0, stream>>>(out, T, flag);
    sim_nospike<<<(NT + 63) / 64, 64, 0, stream>>>(Input, dt, out, T, flag);
    fallback<<<1, 1024, 0, stream>>>(Input, conn, Wout, dt, tauE, tauI, out, T, flag);
}